// Round 9
// baseline (2650.787 us; speedup 1.0000x reference)
//
#include <hip/hip_runtime.h>
#include <math.h>

#define BBATCH 32
#define NTOK 197
#define NPATCH 196
#define PDIM 768
#define DDIM 512
#define NHEAD 8
#define DHEAD 64
#define MLPDIM 2048
#define NLAYER 10
#define NCLASS 10
#define MTOK (BBATCH*NTOK)      // 6304
#define MPAD 6400               // padded rows (25*256)
#define MPATCH (BBATCH*NPATCH)  // 6272
#define QKVROWS (MTOK + 16)

typedef unsigned short u16;
typedef __attribute__((ext_vector_type(8))) short bf16x8;
typedef __attribute__((ext_vector_type(4))) float f32x4;

__device__ __forceinline__ float gelu_f(float x) {
    return 0.5f * x * (1.0f + erff(x * 0.70710678118654752440f));
}
__device__ __forceinline__ float bf2f(u16 u) {
    union { unsigned int i; float f; } v; v.i = ((unsigned int)u) << 16; return v.f;
}
__device__ __forceinline__ u16 f2bf(float f) {
    union { float f; unsigned int u; } v; v.f = f;
    unsigned int r = v.u + 0x7FFFu + ((v.u >> 16) & 1u);
    return (u16)(r >> 16);
}
__device__ __forceinline__ void gload_lds16(const u16* g, u16* l) {
    __builtin_amdgcn_global_load_lds((const __attribute__((address_space(1))) void*)g,
                                     (__attribute__((address_space(3))) void*)l, 16, 0, 0);
}
__device__ __forceinline__ int swz_bij(int wg, int nwg) {
    int q = nwg >> 3, r = nwg & 7, xcd = wg & 7, id8 = wg >> 3;
    return (xcd < r) ? xcd * (q + 1) + id8 : r * (q + 1) + (xcd - r) * q + id8;
}

// ---------------------------------------------------------------------------
// 256x128-tile bf16 MFMA GEMM (K=512, nk=8), 512 thr = 8 waves (4Mx2N),
// 64x64/wave.  T3-style interleaved 2-phase-per-K-tile schedule:
//   Ph1: issue 3 stage loads(t+1) ; vmcnt(3) ; barrier ; ds_read kk0 ;
//        setprio(1) 16xMFMA setprio(0) ; barrier
//   Ph2: issue 3 stage loads(t+1) ; ds_read kk1 ; setprio MFMA ; barrier
// Counted vmcnt never drains next tile's loads (T4).  Dbuf LDS 96 KB.
// Two regions per dispatch.  Modes: 0 bf16-out, 1 halt-reduce, 2 gelu-bf16.
// ---------------------------------------------------------------------------
template<int MODEA, int MODEB>
__global__ __launch_bounds__(512)
void gemm256_kernel(int nA, int colsA, int colsB,
                    const u16* __restrict__ Aa, const u16* __restrict__ Wa,
                    const float* __restrict__ biasa, void* __restrict__ outa, int Na,
                    const u16* __restrict__ Ab, const u16* __restrict__ Wb,
                    const float* __restrict__ biasb, const float* __restrict__ wh2,
                    void* __restrict__ outb, int Nb, int M)
{
    __shared__ u16 As[2][256 * 64];
    __shared__ u16 Bs[2][128 * 64];
    const int tid = threadIdx.x, lane = tid & 63, wid = tid >> 6;
    const int wr = wid >> 1, wc = wid & 1;

    const int swz = swz_bij(blockIdx.x, gridDim.x);
    int mode, m0, n0, Nn;
    const u16 *A, *W; const float* bias; void* out;
    if (swz < nA) {
        mode = MODEA; A = Aa; W = Wa; bias = biasa; out = outa; Nn = Na;
        m0 = (swz / colsA) * 256; n0 = (swz % colsA) * 128;
    } else {
        int s2 = swz - nA;
        mode = MODEB; A = Ab; W = Wb; bias = biasb; out = outb; Nn = Nb;
        m0 = (s2 / colsB) * 256; n0 = (s2 % colsB) * 128;
    }

    f32x4 acc[4][4] = {};
    const int srow = tid >> 3;          // 0..63
    const int dcb  = (tid & 7) << 4;

    auto stageA3 = [&](int buf, int k0) {     // A panels p=0..2 (3 loads)
        #pragma unroll
        for (int p = 0; p < 3; ++p) {
            int rr = p * 64 + srow;
            int scb = dcb ^ ((rr & 7) << 4);
            gload_lds16(A + (size_t)(m0 + rr) * 512 + k0 + (scb >> 1), &As[buf][p * 4096 + tid * 8]);
        }
    };
    auto stageB3 = [&](int buf, int k0) {     // A p=3 + B p=0,1 (3 loads)
        {
            int rr = 192 + srow;
            int scb = dcb ^ ((rr & 7) << 4);
            gload_lds16(A + (size_t)(m0 + rr) * 512 + k0 + (scb >> 1), &As[buf][3 * 4096 + tid * 8]);
        }
        #pragma unroll
        for (int p = 0; p < 2; ++p) {
            int rr = p * 64 + srow;
            int scb = dcb ^ ((rr & 7) << 4);
            gload_lds16(W + (size_t)(n0 + rr) * 512 + k0 + (scb >> 1), &Bs[buf][p * 4096 + tid * 8]);
        }
    };
    auto phase = [&](int buf, int kk) {
        const int kb = (kk + ((lane >> 4) << 3)) << 1;
        bf16x8 af[4], bfr[4];
        #pragma unroll
        for (int mi = 0; mi < 4; ++mi) {
            int ar = wr * 64 + mi * 16 + (lane & 15);
            af[mi] = *(const bf16x8*)&As[buf][ar * 64 + ((kb ^ ((ar & 7) << 4)) >> 1)];
        }
        #pragma unroll
        for (int ni = 0; ni < 4; ++ni) {
            int br = wc * 64 + ni * 16 + (lane & 15);
            bfr[ni] = *(const bf16x8*)&Bs[buf][br * 64 + ((kb ^ ((br & 7) << 4)) >> 1)];
        }
        __builtin_amdgcn_s_setprio(1);
        #pragma unroll
        for (int mi = 0; mi < 4; ++mi)
            #pragma unroll
            for (int ni = 0; ni < 4; ++ni)
                acc[mi][ni] = __builtin_amdgcn_mfma_f32_16x16x32_bf16(
                    af[mi], bfr[ni], acc[mi][ni], 0, 0, 0);
        __builtin_amdgcn_s_setprio(0);
    };

    // prologue: tile 0's 6 loads
    stageA3(0, 0); stageB3(0, 0);
    int cur = 0;
    #pragma unroll 1
    for (int t = 0; t < 8; ++t) {               // K=512 -> 8 K-tiles
        const int kn = (t + 1) << 6;
        // Phase 1
        if (t < 7) {
            stageA3(cur ^ 1, kn);
            asm volatile("s_waitcnt vmcnt(3)" ::: "memory");   // tile t's 6 done
        } else {
            asm volatile("s_waitcnt vmcnt(0)" ::: "memory");
        }
        __builtin_amdgcn_s_barrier();
        phase(cur, 0);
        __builtin_amdgcn_s_barrier();
        // Phase 2
        if (t < 7) stageB3(cur ^ 1, kn);
        phase(cur, 32);
        __builtin_amdgcn_s_barrier();
        cur ^= 1;
    }

    if (mode == 1) {
        float* hout = (float*)out;
        #pragma unroll
        for (int mi = 0; mi < 4; ++mi) {
            #pragma unroll
            for (int j = 0; j < 4; ++j) {
                int row = m0 + wr * 64 + mi * 16 + ((lane >> 4) << 2) + j;
                float part = 0.0f;
                #pragma unroll
                for (int ni = 0; ni < 4; ++ni) {
                    int col = n0 + wc * 64 + ni * 16 + (lane & 15);
                    part += gelu_f(acc[mi][ni][j] + bias[col]) * wh2[col];
                }
                #pragma unroll
                for (int off = 1; off < 16; off <<= 1) part += __shfl_xor(part, off, 64);
                if ((lane & 15) == 0 && row < M) atomicAdd(&hout[row], part);
            }
        }
        return;
    }
    u16* outb16 = (u16*)out;
    #pragma unroll
    for (int mi = 0; mi < 4; ++mi) {
        #pragma unroll
        for (int j = 0; j < 4; ++j) {
            int row = m0 + wr * 64 + mi * 16 + ((lane >> 4) << 2) + j;
            if (row >= M) continue;
            #pragma unroll
            for (int ni = 0; ni < 4; ++ni) {
                int col = n0 + wc * 64 + ni * 16 + (lane & 15);
                float v = acc[mi][ni][j];
                if (mode == 2) v = gelu_f(v + bias[col]);
                outb16[(size_t)row * Nn + col] = f2bf(v);
            }
        }
    }
}

// ---------------------------------------------------------------------------
// 128x128-tile bf16 MFMA GEMM, 256 thr = 4 waves, dbuf 64 KB (2 blocks/CU),
// same T3-style interleaved 2-phase schedule (8 loads/tile, halves of 4).
// Modes: 3 = f32 out = acc + bias (+ res[row][col] if res)
//        4 = f32 atomicAdd out += acc (+ bias[col] if bias)   [split-K]
//        2 = gelu(acc+bias) -> bf16 out
// ---------------------------------------------------------------------------
template<int MODE>
__global__ __launch_bounds__(256)
void mg_kernel(const u16* __restrict__ A, const u16* __restrict__ W,
               const float* __restrict__ bias, const float* __restrict__ res,
               void* __restrict__ Cout, int M, int Nn, int K,
               int cols, int kb, int nk, int mtiles)
{
    __shared__ u16 As[2][128 * 64];
    __shared__ u16 Bs[2][128 * 64];
    const int tid = threadIdx.x, lane = tid & 63, wid = tid >> 6;
    const int wr = wid >> 1, wc = wid & 1;

    const int swz = swz_bij(blockIdx.x, gridDim.x);
    const int ti = swz % (mtiles * cols);     // tile within (possibly split-K) slab
    const int ks = swz / (mtiles * cols);     // split-K index
    const int m0 = (ti / cols) * 128, n0 = (ti % cols) * 128;
    const int kbase = kb + ks * (nk << 6);

    f32x4 acc[4][4] = {};
    const int srow = tid >> 3;
    const int dcb  = (tid & 7) << 4;

    auto stage_h = [&](int buf, int k0, int pb) {
        #pragma unroll
        for (int p = 0; p < 2; ++p) {
            int rr = (pb + p) * 32 + srow;
            int scb = dcb ^ ((rr & 7) << 4);
            gload_lds16(A + (size_t)(m0 + rr) * K + k0 + (scb >> 1), &As[buf][(pb + p) * 2048 + tid * 8]);
            gload_lds16(W + (size_t)(n0 + rr) * K + k0 + (scb >> 1), &Bs[buf][(pb + p) * 2048 + tid * 8]);
        }
    };
    auto phase = [&](int buf, int kk) {
        const int kbyte = (kk + ((lane >> 4) << 3)) << 1;
        bf16x8 af[4], bfr[4];
        #pragma unroll
        for (int mi = 0; mi < 4; ++mi) {
            int ar = wr * 64 + mi * 16 + (lane & 15);
            af[mi] = *(const bf16x8*)&As[buf][ar * 64 + ((kbyte ^ ((ar & 7) << 4)) >> 1)];
        }
        #pragma unroll
        for (int ni = 0; ni < 4; ++ni) {
            int br = wc * 64 + ni * 16 + (lane & 15);
            bfr[ni] = *(const bf16x8*)&Bs[buf][br * 64 + ((kbyte ^ ((br & 7) << 4)) >> 1)];
        }
        __builtin_amdgcn_s_setprio(1);
        #pragma unroll
        for (int mi = 0; mi < 4; ++mi)
            #pragma unroll
            for (int ni = 0; ni < 4; ++ni)
                acc[mi][ni] = __builtin_amdgcn_mfma_f32_16x16x32_bf16(
                    af[mi], bfr[ni], acc[mi][ni], 0, 0, 0);
        __builtin_amdgcn_s_setprio(0);
    };

    stage_h(0, kbase, 0); stage_h(0, kbase, 2);   // 8 loads
    int cur = 0;
    #pragma unroll 1
    for (int t = 0; t < nk; ++t) {
        const int kn = kbase + ((t + 1) << 6);
        if (t < nk - 1) {
            stage_h(cur ^ 1, kn, 0);
            asm volatile("s_waitcnt vmcnt(4)" ::: "memory");
        } else {
            asm volatile("s_waitcnt vmcnt(0)" ::: "memory");
        }
        __builtin_amdgcn_s_barrier();
        phase(cur, 0);
        __builtin_amdgcn_s_barrier();
        if (t < nk - 1) stage_h(cur ^ 1, kn, 2);
        phase(cur, 32);
        __builtin_amdgcn_s_barrier();
        cur ^= 1;
    }

    if (MODE == 4) {
        float* outf = (float*)Cout;
        #pragma unroll
        for (int mi = 0; mi < 4; ++mi)
            #pragma unroll
            for (int j = 0; j < 4; ++j) {
                int row = m0 + wr * 64 + mi * 16 + ((lane >> 4) << 2) + j;
                if (row >= M) continue;
                #pragma unroll
                for (int ni = 0; ni < 4; ++ni) {
                    int col = n0 + wc * 64 + ni * 16 + (lane & 15);
                    float v = acc[mi][ni][j];
                    if (bias && ks == 0) v += bias[col];
                    atomicAdd(&outf[(size_t)row * Nn + col], v);
                }
            }
        return;
    }
    if (MODE == 3) {
        float* outf = (float*)Cout;
        #pragma unroll
        for (int mi = 0; mi < 4; ++mi)
            #pragma unroll
            for (int j = 0; j < 4; ++j) {
                int row = m0 + wr * 64 + mi * 16 + ((lane >> 4) << 2) + j;
                if (row >= M) continue;
                #pragma unroll
                for (int ni = 0; ni < 4; ++ni) {
                    int col = n0 + wc * 64 + ni * 16 + (lane & 15);
                    float v = acc[mi][ni][j] + bias[col];
                    if (res) v += res[(size_t)row * Nn + col];
                    outf[(size_t)row * Nn + col] = v;
                }
            }
        return;
    }
    // MODE == 2
    u16* ob16 = (u16*)Cout;
    #pragma unroll
    for (int mi = 0; mi < 4; ++mi)
        #pragma unroll
        for (int j = 0; j < 4; ++j) {
            int row = m0 + wr * 64 + mi * 16 + ((lane >> 4) << 2) + j;
            if (row >= M) continue;
            #pragma unroll
            for (int ni = 0; ni < 4; ++ni) {
                int col = n0 + wc * 64 + ni * 16 + (lane & 15);
                ob16[(size_t)row * Nn + col] = f2bf(gelu_f(acc[mi][ni][j] + bias[col]));
            }
        }
}

// ---------------------------------------------------------------------------
// LayerNorm: one wave per row (grid-strided), fp32 in, one or two bf16 outs.
// ---------------------------------------------------------------------------
__global__ __launch_bounds__(256)
void ln_one_kernel(const float* __restrict__ X, const float* __restrict__ g,
                   const float* __restrict__ bb, u16* __restrict__ Y, int M)
{
    int w0 = blockIdx.x * 4 + (threadIdx.x >> 6);
    int lane = threadIdx.x & 63;
    int stride = gridDim.x * 4;
    for (int row = w0; row < M; row += stride) {
        const float* x = X + (size_t)row * DDIM;
        float v[8], s = 0.0f;
        #pragma unroll
        for (int i = 0; i < 8; i++) { v[i] = x[lane + i * 64]; s += v[i]; }
        #pragma unroll
        for (int off = 32; off; off >>= 1) s += __shfl_xor(s, off, 64);
        float mu = s * (1.0f / 512.0f), q = 0.0f;
        #pragma unroll
        for (int i = 0; i < 8; i++) { float d = v[i] - mu; q += d * d; }
        #pragma unroll
        for (int off = 32; off; off >>= 1) q += __shfl_xor(q, off, 64);
        float inv = 1.0f / sqrtf(q * (1.0f / 512.0f) + 1e-5f);
        u16* y = Y + (size_t)row * DDIM;
        #pragma unroll
        for (int i = 0; i < 8; i++) {
            int c = lane + i * 64;
            y[c] = f2bf((v[i] - mu) * inv * g[c] + bb[c]);
        }
    }
}

__global__ __launch_bounds__(256)
void ln_dual_kernel(const float* __restrict__ X,
                    const float* __restrict__ g1, const float* __restrict__ b1,
                    const float* __restrict__ g2, const float* __restrict__ b2,
                    u16* __restrict__ Y1, u16* __restrict__ Y2, int M)
{
    int w0 = blockIdx.x * 4 + (threadIdx.x >> 6);
    int lane = threadIdx.x & 63;
    int stride = gridDim.x * 4;
    for (int row = w0; row < M; row += stride) {
        const float* x = X + (size_t)row * DDIM;
        float v[8], s = 0.0f;
        #pragma unroll
        for (int i = 0; i < 8; i++) { v[i] = x[lane + i * 64]; s += v[i]; }
        #pragma unroll
        for (int off = 32; off; off >>= 1) s += __shfl_xor(s, off, 64);
        float mu = s * (1.0f / 512.0f), q = 0.0f;
        #pragma unroll
        for (int i = 0; i < 8; i++) { float d = v[i] - mu; q += d * d; }
        #pragma unroll
        for (int off = 32; off; off >>= 1) q += __shfl_xor(q, off, 64);
        float inv = 1.0f / sqrtf(q * (1.0f / 512.0f) + 1e-5f);
        u16* y1 = Y1 + (size_t)row * DDIM;
        u16* y2 = Y2 + (size_t)row * DDIM;
        #pragma unroll
        for (int i = 0; i < 8; i++) {
            int c = lane + i * 64;
            float n = (v[i] - mu) * inv;
            y1[c] = f2bf(n * g1[c] + b1[c]);
            y2[c] = f2bf(n * g2[c] + b2[c]);
        }
    }
}

__global__ __launch_bounds__(256)
void patch_kernel(const float* __restrict__ x, u16* __restrict__ xp)
{
    const size_t total = (size_t)MPATCH * PDIM;
    for (size_t idx = (size_t)blockIdx.x * 256 + threadIdx.x; idx < total;
         idx += (size_t)gridDim.x * 256) {
        int pd = (int)(idx % PDIM);
        int bn = (int)(idx / PDIM);
        int n = bn % NPATCH, b = bn / NPATCH;
        int c = pd % 3, pix = pd / 3;
        int px = pix % 16, py = pix / 16;
        int hx = n % 14, hy = n / 14;
        int row = hy * 16 + py, col = hx * 16 + px;
        xp[idx] = f2bf(x[((size_t)(b * 3 + c) * 224 + row) * 224 + col]);
    }
}

__global__ __launch_bounds__(256)
void assemble_kernel(const float* __restrict__ e, const float* __restrict__ clstok,
                     const float* __restrict__ pos, float* __restrict__ U)
{
    const size_t total = (size_t)MTOK * DDIM;
    for (size_t idx = (size_t)blockIdx.x * 256 + threadIdx.x; idx < total;
         idx += (size_t)gridDim.x * 256) {
        int d = (int)(idx % DDIM);
        int bt = (int)(idx / DDIM);
        int t = bt % NTOK, b = bt / NTOK;
        float v = (t == 0) ? clstok[d] : e[((size_t)b * NPATCH + (t - 1)) * DDIM + d];
        U[idx] = v + pos[t * DDIM + d];
    }
}

__global__ __launch_bounds__(256)
void convert7_kernel(const float* s0, const float* s1, const float* s2,
                     const float* s3, const float* s4, const float* s5,
                     const float* s6, u16* __restrict__ dst)
{
    const int total4 = 1409024;  // 5636096/4
    for (int i4 = blockIdx.x * 256 + threadIdx.x; i4 < total4; i4 += gridDim.x * 256) {
        size_t e = (size_t)i4 * 4;
        const float* s; size_t off;
        if      (e < 393216)  { s = s0; off = 0; }
        else if (e < 1179648) { s = s1; off = 393216; }
        else if (e < 1441792) { s = s2; off = 1179648; }
        else if (e < 2490368) { s = s3; off = 1441792; }
        else if (e < 3538944) { s = s4; off = 2490368; }
        else if (e < 4587520) { s = s5; off = 3538944; }
        else                  { s = s6; off = 4587520; }
        float4 v = ((const float4*)s)[(e - off) >> 2];
        dst[e + 0] = f2bf(v.x); dst[e + 1] = f2bf(v.y);
        dst[e + 2] = f2bf(v.z); dst[e + 3] = f2bf(v.w);
    }
}

// ---------------------------------------------------------------------------
// MFMA attention (blocks 0..511) with optional fused halt-mean (blocks 512+).
// ---------------------------------------------------------------------------
template<int HM>
__global__ __launch_bounds__(256)
void attn_hm_kernel(const u16* __restrict__ qkv, u16* __restrict__ O,
                    const float* __restrict__ hsc, const float* __restrict__ bh2,
                    const float* __restrict__ U, float* __restrict__ halts,
                    float* __restrict__ cls, int lidx)
{
    __shared__ u16 Ks[208 * 64];
    __shared__ u16 Vt[64 * 208];
    __shared__ u16 Pl[4 * 16 * 208];

    if (HM && blockIdx.x >= 512) {
        int b = blockIdx.x - 512;
        int ln = threadIdx.x;
        if (ln >= 64) return;
        float bb = bh2[0];
        float s = 0.0f;
        for (int t = ln; t < NTOK; t += 64)
            s += 1.0f / (1.0f + expf(-(hsc[b * NTOK + t] + bb)));
        #pragma unroll
        for (int off = 32; off; off >>= 1) s += __shfl_xor(s, off, 64);
        if (ln == 0) halts[b * NLAYER + lidx] = s * (1.0f / (float)NTOK);
        for (int d = ln; d < DDIM; d += 64)
            cls[((size_t)b * NLAYER + lidx) * DDIM + d] = U[(size_t)b * NTOK * DDIM + d];
        return;
    }

    const int bh = blockIdx.x >> 1;
    const int half = blockIdx.x & 1;
    const int b = bh >> 3, h = bh & 7;
    const int tid = threadIdx.x;
    const int lane = tid & 63, wid = tid >> 6;
    const size_t base = ((size_t)b * NTOK) * 1536 + (size_t)h * 64;

    {
        int j0 = tid >> 3;
        int d0 = (tid & 7) * 8;
        for (int p = 0; p < 7; ++p) {
            int j = p * 32 + j0;
            if (j < 208) {
                bf16x8 v = {};
                if (j < NTOK) v = *(const bf16x8*)&qkv[base + (size_t)j * 1536 + 512 + d0];
                int byt = (j * 128 + d0 * 2) ^ ((j & 7) << 4);
                *(bf16x8*)((char*)Ks + byt) = v;
            }
        }
    }
    {
        int d = tid & 63;
        int jg = tid >> 6;
        for (int j = jg * 52; j < jg * 52 + 52; ++j) {
            u16 v = (j < NTOK) ? qkv[base + (size_t)j * 1536 + 1024 + d] : (u16)0;
            int byt = (d * 416 + j * 2) ^ ((d & 7) << 4);
            *(u16*)((char*)Vt + byt) = v;
        }
    }
    __syncthreads();

    u16* Pw = Pl + wid * 16 * 208;
    const float scale = 0.04419417382415922f;
    const int t0   = half ? 7 : 0;
    const int tcnt = half ? 6 : 7;
    const int g = lane >> 4;
    const int mycol = lane & 15;

    for (int ti = wid; ti < tcnt; ti += 4) {
        const int r0 = (t0 + ti) * 16;
        bf16x8 qf[2];
        #pragma unroll
        for (int ks = 0; ks < 2; ++ks) {
            int row = r0 + mycol;
            int col = ks * 32 + (g << 3);
            qf[ks] = *(const bf16x8*)&qkv[base + (size_t)row * 1536 + col];
        }
        f32x4 s[13];
        #pragma unroll
        for (int ct = 0; ct < 13; ++ct) s[ct] = (f32x4){0.f, 0.f, 0.f, 0.f};
        __builtin_amdgcn_s_setprio(1);
        #pragma unroll
        for (int ks = 0; ks < 2; ++ks) {
            int kbyte = (ks * 32 + (g << 3)) * 2;
            #pragma unroll
            for (int ct = 0; ct < 13; ++ct) {
                int n = ct * 16 + mycol;
                bf16x8 kf = *(const bf16x8*)((char*)Ks + ((n * 128 + kbyte) ^ ((n & 7) << 4)));
                s[ct] = __builtin_amdgcn_mfma_f32_16x16x32_bf16(qf[ks], kf, s[ct], 0, 0, 0);
            }
        }
        __builtin_amdgcn_s_setprio(0);
        float m[4], sum[4];
        #pragma unroll
        for (int j = 0; j < 4; ++j) m[j] = -1e30f;
        #pragma unroll
        for (int ct = 0; ct < 13; ++ct) {
            bool valid = (ct * 16 + mycol) < NTOK;
            #pragma unroll
            for (int j = 0; j < 4; ++j) {
                float v = valid ? s[ct][j] * scale : -1e30f;
                s[ct][j] = v;
                m[j] = fmaxf(m[j], v);
            }
        }
        #pragma unroll
        for (int off = 1; off < 16; off <<= 1)
            #pragma unroll
            for (int j = 0; j < 4; ++j) m[j] = fmaxf(m[j], __shfl_xor(m[j], off, 64));
        #pragma unroll
        for (int j = 0; j < 4; ++j) sum[j] = 0.0f;
        #pragma unroll
        for (int ct = 0; ct < 13; ++ct)
            #pragma unroll
            for (int j = 0; j < 4; ++j) {
                float e = expf(s[ct][j] - m[j]);
                s[ct][j] = e;
                sum[j] += e;
            }
        #pragma unroll
        for (int off = 1; off < 16; off <<= 1)
            #pragma unroll
            for (int j = 0; j < 4; ++j) sum[j] += __shfl_xor(sum[j], off, 64);
        float inv[4];
        #pragma unroll
        for (int j = 0; j < 4; ++j) inv[j] = 1.0f / sum[j];
        #pragma unroll
        for (int ct = 0; ct < 13; ++ct) {
            int col = ct * 16 + mycol;
            #pragma unroll
            for (int j = 0; j < 4; ++j) {
                int row = (g << 2) + j;
                int byt = (row * 416 + col * 2) ^ ((row & 7) << 4);
                *(u16*)((char*)Pw + byt) = f2bf(s[ct][j] * inv[j]);
            }
        }
        #pragma unroll
        for (int nt = 0; nt < 4; ++nt) {
            f32x4 o = (f32x4){0.f, 0.f, 0.f, 0.f};
            __builtin_amdgcn_s_setprio(1);
            #pragma unroll
            for (int ks = 0; ks < 7; ++ks) {
                bf16x8 pf = {}, vf = {};
                bool live = !(ks == 6 && g >= 2);
                if (live) {
                    int kbyte = (ks * 32 + (g << 3)) * 2;
                    pf = *(const bf16x8*)((char*)Pw + ((mycol * 416 + kbyte) ^ ((mycol & 7) << 4)));
                    int vrow = nt * 16 + mycol;
                    vf = *(const bf16x8*)((char*)Vt + ((vrow * 416 + kbyte) ^ ((vrow & 7) << 4)));
                }
                o = __builtin_amdgcn_mfma_f32_16x16x32_bf16(pf, vf, o, 0, 0, 0);
            }
            __builtin_amdgcn_s_setprio(0);
            #pragma unroll
            for (int j = 0; j < 4; ++j) {
                int grow = r0 + (g << 2) + j;
                if (grow < NTOK)
                    O[((size_t)b * NTOK + grow) * DDIM + h * 64 + nt * 16 + mycol] = f2bf(o[j]);
            }
        }
    }
}

__global__ __launch_bounds__(64)
void haltmean_kernel(const float* __restrict__ hsc, const float* __restrict__ bh2,
                     const float* __restrict__ U, float* __restrict__ halts,
                     float* __restrict__ cls, int lidx)
{
    int b = blockIdx.x, lane = threadIdx.x;
    float bb = bh2[0];
    float s = 0.0f;
    for (int t = lane; t < NTOK; t += 64)
        s += 1.0f / (1.0f + expf(-(hsc[b * NTOK + t] + bb)));
    #pragma unroll
    for (int off = 32; off; off >>= 1) s += __shfl_xor(s, off, 64);
    if (lane == 0) halts[b * NLAYER + lidx] = s * (1.0f / (float)NTOK);
    for (int d = lane; d < DDIM; d += 64)
        cls[((size_t)b * NLAYER + lidx) * DDIM + d] = U[(size_t)b * NTOK * DDIM + d];
}

__global__ __launch_bounds__(256)
void head_logits_kernel(const u16* __restrict__ Hh, const float* __restrict__ Wc2,
                        const float* __restrict__ bc2, float* __restrict__ logits)
{
    int wave = (blockIdx.x * 4) + (threadIdx.x >> 6);
    int lane = threadIdx.x & 63;
    if (wave >= BBATCH * NLAYER) return;
    const u16* row = Hh + (size_t)wave * MLPDIM;
    float rv[32];
    #pragma unroll
    for (int i = 0; i < 32; i++) rv[i] = bf2f(row[lane + i * 64]);
    #pragma unroll
    for (int c = 0; c < NCLASS; c++) {
        float s = 0.0f;
        #pragma unroll
        for (int i = 0; i < 32; i++) s = fmaf(rv[i], Wc2[c * MLPDIM + lane + i * 64], s);
        #pragma unroll
        for (int off = 32; off; off >>= 1) s += __shfl_xor(s, off, 64);
        if (lane == 0) logits[wave * NCLASS + c] = s + bc2[c];
    }
}

__global__ __launch_bounds__(256)
void celoss_kernel(const float* __restrict__ logits, const int* __restrict__ y,
                   const float* __restrict__ halts, float* __restrict__ out)
{
    __shared__ float ceS[BBATCH * NLAYER];
    __shared__ float bl[BBATCH];
    int tid = threadIdx.x;
    for (int r = tid; r < BBATCH * NLAYER; r += 256) {
        const float* lg = logits + (size_t)r * NCLASS;
        float mx = lg[0];
        #pragma unroll
        for (int i = 1; i < NCLASS; i++) mx = fmaxf(mx, lg[i]);
        float s = 0.0f;
        #pragma unroll
        for (int i = 0; i < NCLASS; i++) s += expf(lg[i] - mx);
        int lab = y[r / NLAYER];
        ceS[r] = -(lg[lab] - mx - logf(s));
    }
    __syncthreads();
    if (tid < BBATCH) {
        const float* c = ceS + tid * NLAYER;
        int idx = 0; float mn = c[0];
        for (int l = 1; l < NLAYER; l++) if (c[l] < mn) { mn = c[l]; idx = l; }
        idx += 1;
        float acc = 0.0f;
        for (int l = 0; l < idx; l++) {
            acc += c[l];
            float p = halts[tid * NLAYER + l];
            p = fminf(fmaxf(p, 1e-7f), 1.0f - 1e-7f);
            float hl = (l == idx - 1) ? 0.0f : 1.0f;
            acc += -(hl * logf(p) + (1.0f - hl) * log1pf(-p));
        }
        bl[tid] = acc / (float)idx;
    }
    __syncthreads();
    if (tid == 0) {
        float t = 0.0f;
        for (int b = 0; b < BBATCH; b++) t += bl[b];
        out[0] = t * (1.0f / (float)BBATCH);
    }
}

extern "C" void kernel_launch(void* const* d_in, const int* in_sizes, int n_in,
                              void* d_out, int out_size, void* d_ws, size_t ws_size,
                              hipStream_t stream)
{
    const float* x      = (const float*)d_in[0];
    const int*   y      = (const int*)d_in[1];
    const float* pos    = (const float*)d_in[2];
    const float* clstok = (const float*)d_in[3];
    const float* Wp     = (const float*)d_in[4];
    const float* bp     = (const float*)d_in[5];
    const float* Wqkv   = (const float*)d_in[6];
    const float* Wo     = (const float*)d_in[7];
    const float* bo     = (const float*)d_in[8];
    const float* ln1g   = (const float*)d_in[9];
    const float* ln1b   = (const float*)d_in[10];
    const float* ln2g   = (const float*)d_in[11];
    const float* ln2b   = (const float*)d_in[12];
    const float* W1     = (const float*)d_in[13];
    const float* b1     = (const float*)d_in[14];
    const float* W2     = (const float*)d_in[15];
    const float* b2     = (const float*)d_in[16];
    const float* lnhg   = (const float*)d_in[17];
    const float* lnhb   = (const float*)d_in[18];
    const float* Wh1    = (const float*)d_in[19];
    const float* bh1    = (const float*)d_in[20];
    const float* Wh2    = (const float*)d_in[21];
    const float* bh2    = (const float*)d_in[22];
    const float* lncg   = (const float*)d_in[23];
    const float* lncb   = (const float*)d_in[24];
    const float* Wc1    = (const float*)d_in[25];
    const float* bc1    = (const float*)d_in[26];
    const float* Wc2    = (const float*)d_in[27];
    const float* bc2    = (const float*)d_in[28];

    // ---- workspace layout ----
    float* U      = (float*)d_ws;                         // MTOK*512 f32
    float* CLS    = U + (size_t)MTOK * DDIM;              // 320*512
    float* LOGITS = CLS + (size_t)BBATCH * NLAYER * DDIM; // 3200
    float* HSC    = LOGITS + BBATCH * NLAYER * NCLASS;    // 10*MTOK
    float* HALTS  = HSC + (size_t)NLAYER * MTOK;          // 320
    u16* QKVb = (u16*)(HALTS + BBATCH * NLAYER + 32);     // QKVROWS*1536 (aliases EMB)
    float* EMB = (float*)QKVb;                            // MPATCH*512 f32 (pre-loop only)
    u16* LNB1 = QKVb + (size_t)QKVROWS * 1536;            // MPAD*512
    u16* LNB2 = LNB1 + (size_t)MPAD * DDIM;               // MPAD*512
    u16* LNBh = LNB2 + (size_t)MPAD * DDIM;               // MPAD*512
    u16* HB   = LNBh + (size_t)MPAD * DDIM;               // MPAD*2048 (aliases XP)
    u16* XP   = HB;                                       // MPATCH*768 (pre-loop only)
    u16* CLNB = HB + (size_t)MPAD * MLPDIM;               // 384*512
    u16* wWp  = CLNB + 384 * DDIM;
    u16* wWqkv= wWp   + 512 * 768;
    u16* wWo  = wWqkv + 1536 * 512;
    u16* wW1  = wWo   + 512 * 512;
    u16* wW2  = wW1   + 2048 * 512;
    u16* wWh1 = wW2   + 512 * 2048;
    u16* wWc1 = wWh1  + 2048 * 512;

    dim3 blk(256);
    const float* dummyF = bh2;

    // ---- setup ----
    convert7_kernel<<<dim3(1024), blk, 0, stream>>>(Wp, Wqkv, Wo, W1, W2, Wh1, Wc1, wWp);
    hipMemsetAsync(HSC, 0, (size_t)NLAYER * MTOK * sizeof(float), stream);
    patch_kernel<<<dim3(2048), blk, 0, stream>>>(x, XP);
    mg_kernel<3><<<dim3(196), blk, 0, stream>>>(
        XP, wWp, bp, nullptr, (void*)EMB, MPATCH, DDIM, PDIM, 4, 0, 12, 49);
    assemble_kernel<<<dim3(2048), blk, 0, stream>>>(EMB, clstok, pos, U);
    ln_dual_kernel<<<dim3(512), blk, 0, stream>>>(U, ln1g, ln1b, lnhg, lnhb, LNB1, LNBh, MTOK);

    for (int l = 0; l < NLAYER; l++) {
        // 1: QKV GEMM (+ halt GEMM of layer l-1)
        if (l == 0) {
            gemm256_kernel<0,0><<<dim3(300), dim3(512), 0, stream>>>(
                300, 12, 12, LNB1, wWqkv, nullptr, (void*)QKVb, 1536,
                LNB1, wWqkv, nullptr, nullptr, (void*)QKVb, 1536, MTOK);
        } else {
            gemm256_kernel<0,1><<<dim3(700), dim3(512), 0, stream>>>(
                300, 12, 16, LNB1, wWqkv, nullptr, (void*)QKVb, 1536,
                LNBh, wWh1, bh1, Wh2, (void*)(HSC + (size_t)(l - 1) * MTOK), 2048, MTOK);
        }
        // 2: attn (+ halt-mean of layer l-1)
        if (l == 0) {
            attn_hm_kernel<0><<<dim3(512), blk, 0, stream>>>(
                QKVb, LNB1, nullptr, dummyF, U, HALTS, CLS, 0);
        } else {
            attn_hm_kernel<1><<<dim3(544), blk, 0, stream>>>(
                QKVb, LNB1, HSC + (size_t)(l - 1) * MTOK, bh2, U, HALTS, CLS, l - 1);
        }
        // 3: Wo + bias + residual -> U (f32)
        mg_kernel<3><<<dim3(200), blk, 0, stream>>>(
            LNB1, wWo, bo, U, (void*)U, MTOK, DDIM, DDIM, 4, 0, 8, 50);
        // 4: ln2
        ln_one_kernel<<<dim3(512), blk, 0, stream>>>(U, ln2g, ln2b, LNB2, MTOK);
        // 5: W1 + bias + gelu -> HB (bf16)
        gemm256_kernel<2,2><<<dim3(400), dim3(512), 0, stream>>>(
            400, 16, 16, LNB2, wW1, b1, (void*)HB, 2048,
            LNB2, wW1, b1, nullptr, (void*)HB, 2048, MTOK);
        // 6: W2 split-K2, atomic += into U (bias on ks==0)
        mg_kernel<4><<<dim3(400), blk, 0, stream>>>(
            HB, wW2, b2, nullptr, (void*)U, MTOK, DDIM, MLPDIM, 4, 0, 16, 50);
        // 7: fused ln1 + lnh of new U
        ln_dual_kernel<<<dim3(512), blk, 0, stream>>>(
            U, ln1g, ln1b, lnhg, lnhb, LNB1, LNBh, MTOK);
    }

    // final halt GEMM (layer 9) + halt-mean
    gemm256_kernel<1,1><<<dim3(400), dim3(512), 0, stream>>>(
        400, 16, 16, LNBh, wWh1, bh1, (void*)(HSC + (size_t)9 * MTOK), 2048,
        LNBh, wWh1, bh1, Wh2, (void*)(HSC + (size_t)9 * MTOK), 2048, MTOK);
    haltmean_kernel<<<dim3(BBATCH), dim3(64), 0, stream>>>(
        HSC + (size_t)9 * MTOK, bh2, U, HALTS, CLS, 9);

    // head
    ln_one_kernel<<<dim3(80), blk, 0, stream>>>(CLS, lncg, lncb, CLNB, BBATCH * NLAYER);
    mg_kernel<2><<<dim3(48), blk, 0, stream>>>(
        CLNB, wWc1, bc1, nullptr, (void*)HB, BBATCH * NLAYER, MLPDIM, DDIM, 16, 0, 8, 3);
    head_logits_kernel<<<dim3(80), blk, 0, stream>>>(HB, Wc2, bc2, LOGITS);
    celoss_kernel<<<dim3(1), blk, 0, stream>>>(LOGITS, y, HALTS, (float*)d_out);
}

// Round 10
// 2256.009 us; speedup vs baseline: 1.1750x; 1.1750x over previous
//
#include <hip/hip_runtime.h>
#include <math.h>

#define BBATCH 32
#define NTOK 197
#define NPATCH 196
#define PDIM 768
#define DDIM 512
#define NHEAD 8
#define DHEAD 64
#define MLPDIM 2048
#define NLAYER 10
#define NCLASS 10
#define MTOK (BBATCH*NTOK)      // 6304
#define MPAD 6400               // padded rows (25*256)
#define MPATCH (BBATCH*NPATCH)  // 6272
#define QKVROWS (MTOK + 16)

typedef unsigned short u16;
typedef __attribute__((ext_vector_type(8))) short bf16x8;
typedef __attribute__((ext_vector_type(4))) float f32x4;

__device__ __forceinline__ float gelu_f(float x) {
    return 0.5f * x * (1.0f + erff(x * 0.70710678118654752440f));
}
__device__ __forceinline__ float bf2f(u16 u) {
    union { unsigned int i; float f; } v; v.i = ((unsigned int)u) << 16; return v.f;
}
__device__ __forceinline__ u16 f2bf(float f) {
    union { float f; unsigned int u; } v; v.f = f;
    unsigned int r = v.u + 0x7FFFu + ((v.u >> 16) & 1u);
    return (u16)(r >> 16);
}
__device__ __forceinline__ void gload_lds16(const u16* g, u16* l) {
    __builtin_amdgcn_global_load_lds((const __attribute__((address_space(1))) void*)g,
                                     (__attribute__((address_space(3))) void*)l, 16, 0, 0);
}
__device__ __forceinline__ int swz_bij(int wg, int nwg) {
    int q = nwg >> 3, r = nwg & 7, xcd = wg & 7, id8 = wg >> 3;
    return (xcd < r) ? xcd * (q + 1) + id8 : r * (q + 1) + (xcd - r) * q + id8;
}

// ---------------------------------------------------------------------------
// 256x128-tile bf16 MFMA GEMM (K=512 fixed), 512 thr = 8 waves (4M x 2N),
// per-wave 64x64 (proven micro-kernel).  TRIPLE-buffered, 2-K-tile lookahead,
// counted vmcnt(12) (= exactly the current tile's 6 oldest loads).  Same
// 2-barrier-per-K-tile structure as the best config (R6); only the buffer
// count / lookahead depth changed.
// Two block-modes per dispatch: blocks [0,nA) run MODEA on param-set a,
// the rest MODEB on param-set b.  Modes: 0 = bf16 out (no bias/act),
// 1 = halt (gelu(acc+bias).wh2 -> atomicAdd per-row), 2 = bias+gelu bf16 out.
// ---------------------------------------------------------------------------
template<int MODEA, int MODEB>
__global__ __launch_bounds__(512)
void gemm256_kernel(int nA, int colsA, int colsB,
                    const u16* __restrict__ Aa, const u16* __restrict__ Wa,
                    const float* __restrict__ biasa, void* __restrict__ outa, int Na,
                    const u16* __restrict__ Ab, const u16* __restrict__ Wb,
                    const float* __restrict__ biasb, const float* __restrict__ wh2,
                    void* __restrict__ outb, int Nb, int M)
{
    __shared__ u16 As[3][256 * 64];   // 96 KB
    __shared__ u16 Bs[3][128 * 64];   // 48 KB  (total 144 KB, 1 block/CU)
    const int tid = threadIdx.x, lane = tid & 63, wid = tid >> 6;
    const int wr = wid >> 1, wc = wid & 1;

    const int swz = swz_bij(blockIdx.x, gridDim.x);
    int mode, m0, n0, Nn;
    const u16 *A, *W; const float* bias; void* out;
    if (swz < nA) {
        mode = MODEA; A = Aa; W = Wa; bias = biasa; out = outa; Nn = Na;
        m0 = (swz / colsA) * 256; n0 = (swz % colsA) * 128;
    } else {
        int s2 = swz - nA;
        mode = MODEB; A = Ab; W = Wb; bias = biasb; out = outb; Nn = Nb;
        m0 = (s2 / colsB) * 256; n0 = (s2 % colsB) * 128;
    }

    f32x4 acc[4][4] = {};
    const int srow = tid >> 3;          // 0..63
    const int dcb  = (tid & 7) << 4;

    auto stage = [&](int buf, int k0) {
        #pragma unroll
        for (int p = 0; p < 4; ++p) {
            int rr = p * 64 + srow;
            int scb = dcb ^ ((rr & 7) << 4);
            gload_lds16(A + (size_t)(m0 + rr) * 512 + k0 + (scb >> 1), &As[buf][p * 4096 + tid * 8]);
        }
        #pragma unroll
        for (int p = 0; p < 2; ++p) {
            int rr = p * 64 + srow;
            int scb = dcb ^ ((rr & 7) << 4);
            gload_lds16(W + (size_t)(n0 + rr) * 512 + k0 + (scb >> 1), &Bs[buf][p * 4096 + tid * 8]);
        }
    };
    auto compute = [&](int buf) {
        #pragma unroll
        for (int kk = 0; kk < 64; kk += 32) {
            const int kb = (kk + ((lane >> 4) << 3)) << 1;
            bf16x8 af[4], bfr[4];
            #pragma unroll
            for (int mi = 0; mi < 4; ++mi) {
                int ar = wr * 64 + mi * 16 + (lane & 15);
                af[mi] = *(const bf16x8*)&As[buf][ar * 64 + ((kb ^ ((ar & 7) << 4)) >> 1)];
            }
            #pragma unroll
            for (int ni = 0; ni < 4; ++ni) {
                int br = wc * 64 + ni * 16 + (lane & 15);
                bfr[ni] = *(const bf16x8*)&Bs[buf][br * 64 + ((kb ^ ((br & 7) << 4)) >> 1)];
            }
            #pragma unroll
            for (int mi = 0; mi < 4; ++mi)
                #pragma unroll
                for (int ni = 0; ni < 4; ++ni)
                    acc[mi][ni] = __builtin_amdgcn_mfma_f32_16x16x32_bf16(
                        af[mi], bfr[ni], acc[mi][ni], 0, 0, 0);
        }
    };

    // prologue: tiles 0 and 1 (12 loads outstanding)
    stage(0, 0); stage(1, 64);
    #pragma unroll 1
    for (int t = 0; t < 8; ++t) {               // K=512 -> 8 K-tiles
        if (t < 6) {
            stage((t + 2) % 3, (t + 2) << 6);   // 2-tile lookahead
            asm volatile("s_waitcnt vmcnt(12)" ::: "memory");  // tile t's 6 done
        } else if (t == 6) {
            asm volatile("s_waitcnt vmcnt(6)" ::: "memory");
        } else {
            asm volatile("s_waitcnt vmcnt(0)" ::: "memory");
        }
        __builtin_amdgcn_s_barrier();
        compute(t % 3);
        __builtin_amdgcn_s_barrier();
    }

    if (mode == 1) {
        float* hout = (float*)out;
        #pragma unroll
        for (int mi = 0; mi < 4; ++mi) {
            #pragma unroll
            for (int j = 0; j < 4; ++j) {
                int row = m0 + wr * 64 + mi * 16 + ((lane >> 4) << 2) + j;
                float part = 0.0f;
                #pragma unroll
                for (int ni = 0; ni < 4; ++ni) {
                    int col = n0 + wc * 64 + ni * 16 + (lane & 15);
                    part += gelu_f(acc[mi][ni][j] + bias[col]) * wh2[col];
                }
                #pragma unroll
                for (int off = 1; off < 16; off <<= 1) part += __shfl_xor(part, off, 64);
                if ((lane & 15) == 0 && row < M) atomicAdd(&hout[row], part);
            }
        }
        return;
    }
    u16* outb16 = (u16*)out;
    #pragma unroll
    for (int mi = 0; mi < 4; ++mi) {
        #pragma unroll
        for (int j = 0; j < 4; ++j) {
            int row = m0 + wr * 64 + mi * 16 + ((lane >> 4) << 2) + j;
            if (row >= M) continue;
            #pragma unroll
            for (int ni = 0; ni < 4; ++ni) {
                int col = n0 + wc * 64 + ni * 16 + (lane & 15);
                float v = acc[mi][ni][j];
                if (mode == 2) v = gelu_f(v + bias[col]);
                outb16[(size_t)row * Nn + col] = f2bf(v);
            }
        }
    }
}

// ---------------------------------------------------------------------------
// 128x128 bf16 MFMA GEMM with optional split-K (ATOMIC accumulate into fp32).
// Double-buffered, counted vmcnt(8), 2 barriers/K-tile (R6-proven).
// gridDim.y = mtiles * nsplit; kbase = ks*kcount.
// ---------------------------------------------------------------------------
template<int ACT, int HASB, int HASR, int OUTBF, int ATOMIC>
__global__ __launch_bounds__(256)
void mgemm_kernel(const u16* __restrict__ A, const u16* __restrict__ W,
                  const float* __restrict__ bias, const float* __restrict__ res,
                  void* __restrict__ Cout, int M, int Nn, int K, int kcount, int mtiles)
{
    __shared__ u16 As[2][128 * 64];
    __shared__ u16 Bs[2][128 * 64];
    const int tid = threadIdx.x, lane = tid & 63, wid = tid >> 6;
    const int wr = wid >> 1, wc = wid & 1;

    const int gx = gridDim.x;
    const int swz = swz_bij(blockIdx.y * gx + blockIdx.x, gx * gridDim.y);
    const int ry = swz / gx;
    const int ks = ry / mtiles;
    const int m0 = (ry % mtiles) * 128, n0 = (swz % gx) * 128;
    const int kbase = ks * kcount;

    f32x4 acc[4][4] = {};
    const int srow = tid >> 3;
    const int dcb  = (tid & 7) << 4;

    auto stage = [&](int buf, int k0) {
        #pragma unroll
        for (int p = 0; p < 4; ++p) {
            int rr = p * 32 + srow;
            int scb = dcb ^ ((rr & 7) << 4);
            gload_lds16(A + (size_t)(m0 + rr) * K + k0 + (scb >> 1), &As[buf][p * 2048 + tid * 8]);
            gload_lds16(W + (size_t)(n0 + rr) * K + k0 + (scb >> 1), &Bs[buf][p * 2048 + tid * 8]);
        }
    };
    auto compute = [&](int buf) {
        #pragma unroll
        for (int kk = 0; kk < 64; kk += 32) {
            const int kb = (kk + ((lane >> 4) << 3)) << 1;
            bf16x8 af[4], bfr[4];
            #pragma unroll
            for (int mi = 0; mi < 4; ++mi) {
                int ar = wr * 64 + mi * 16 + (lane & 15);
                af[mi] = *(const bf16x8*)&As[buf][ar * 64 + ((kb ^ ((ar & 7) << 4)) >> 1)];
            }
            #pragma unroll
            for (int ni = 0; ni < 4; ++ni) {
                int br = wc * 64 + ni * 16 + (lane & 15);
                bfr[ni] = *(const bf16x8*)&Bs[buf][br * 64 + ((kb ^ ((br & 7) << 4)) >> 1)];
            }
            #pragma unroll
            for (int mi = 0; mi < 4; ++mi)
                #pragma unroll
                for (int ni = 0; ni < 4; ++ni)
                    acc[mi][ni] = __builtin_amdgcn_mfma_f32_16x16x32_bf16(
                        af[mi], bfr[ni], acc[mi][ni], 0, 0, 0);
        }
    };

    const int NT = kcount >> 6;
    stage(0, kbase);
    int cur = 0;
    #pragma unroll 1
    for (int t = 0; t < NT - 1; ++t) {
        stage(cur ^ 1, kbase + ((t + 1) << 6));
        asm volatile("s_waitcnt vmcnt(8)" ::: "memory");
        __builtin_amdgcn_s_barrier();
        compute(cur);
        __builtin_amdgcn_s_barrier();
        cur ^= 1;
    }
    asm volatile("s_waitcnt vmcnt(0)" ::: "memory");
    __builtin_amdgcn_s_barrier();
    compute(cur);

    float* outf = (float*)Cout;
    u16*   outb = (u16*)Cout;
    #pragma unroll
    for (int mi = 0; mi < 4; ++mi) {
        #pragma unroll
        for (int j = 0; j < 4; ++j) {
            int row = m0 + wr * 64 + mi * 16 + ((lane >> 4) << 2) + j;
            if (row >= M) continue;
            #pragma unroll
            for (int ni = 0; ni < 4; ++ni) {
                int col = n0 + wc * 64 + ni * 16 + (lane & 15);
                float v = acc[mi][ni][j];
                if (ATOMIC) {
                    if (HASB && ks == 0) v += bias[col];
                    atomicAdd(&outf[(size_t)row * Nn + col], v);
                } else {
                    if (HASB) v += bias[col];
                    if (ACT)  v = gelu_f(v);
                    if (HASR) v += res[(size_t)row * Nn + col];
                    if (OUTBF) outb[(size_t)row * Nn + col] = f2bf(v);
                    else       outf[(size_t)row * Nn + col] = v;
                }
            }
        }
    }
}

// ---------------------------------------------------------------------------
// LayerNorm: one wave per row (grid-strided), fp32 in, one or two bf16 outs.
// ---------------------------------------------------------------------------
__global__ __launch_bounds__(256)
void ln_one_kernel(const float* __restrict__ X, const float* __restrict__ g,
                   const float* __restrict__ bb, u16* __restrict__ Y, int M)
{
    int w0 = blockIdx.x * 4 + (threadIdx.x >> 6);
    int lane = threadIdx.x & 63;
    int stride = gridDim.x * 4;
    for (int row = w0; row < M; row += stride) {
        const float* x = X + (size_t)row * DDIM;
        float v[8], s = 0.0f;
        #pragma unroll
        for (int i = 0; i < 8; i++) { v[i] = x[lane + i * 64]; s += v[i]; }
        #pragma unroll
        for (int off = 32; off; off >>= 1) s += __shfl_xor(s, off, 64);
        float mu = s * (1.0f / 512.0f), q = 0.0f;
        #pragma unroll
        for (int i = 0; i < 8; i++) { float d = v[i] - mu; q += d * d; }
        #pragma unroll
        for (int off = 32; off; off >>= 1) q += __shfl_xor(q, off, 64);
        float inv = 1.0f / sqrtf(q * (1.0f / 512.0f) + 1e-5f);
        u16* y = Y + (size_t)row * DDIM;
        #pragma unroll
        for (int i = 0; i < 8; i++) {
            int c = lane + i * 64;
            y[c] = f2bf((v[i] - mu) * inv * g[c] + bb[c]);
        }
    }
}

__global__ __launch_bounds__(256)
void ln_dual_kernel(const float* __restrict__ X,
                    const float* __restrict__ g1, const float* __restrict__ b1,
                    const float* __restrict__ g2, const float* __restrict__ b2,
                    u16* __restrict__ Y1, u16* __restrict__ Y2, int M)
{
    int w0 = blockIdx.x * 4 + (threadIdx.x >> 6);
    int lane = threadIdx.x & 63;
    int stride = gridDim.x * 4;
    for (int row = w0; row < M; row += stride) {
        const float* x = X + (size_t)row * DDIM;
        float v[8], s = 0.0f;
        #pragma unroll
        for (int i = 0; i < 8; i++) { v[i] = x[lane + i * 64]; s += v[i]; }
        #pragma unroll
        for (int off = 32; off; off >>= 1) s += __shfl_xor(s, off, 64);
        float mu = s * (1.0f / 512.0f), q = 0.0f;
        #pragma unroll
        for (int i = 0; i < 8; i++) { float d = v[i] - mu; q += d * d; }
        #pragma unroll
        for (int off = 32; off; off >>= 1) q += __shfl_xor(q, off, 64);
        float inv = 1.0f / sqrtf(q * (1.0f / 512.0f) + 1e-5f);
        u16* y1 = Y1 + (size_t)row * DDIM;
        u16* y2 = Y2 + (size_t)row * DDIM;
        #pragma unroll
        for (int i = 0; i < 8; i++) {
            int c = lane + i * 64;
            float n = (v[i] - mu) * inv;
            y1[c] = f2bf(n * g1[c] + b1[c]);
            y2[c] = f2bf(n * g2[c] + b2[c]);
        }
    }
}

__global__ __launch_bounds__(256)
void patch_kernel(const float* __restrict__ x, u16* __restrict__ xp)
{
    const size_t total = (size_t)MPATCH * PDIM;
    for (size_t idx = (size_t)blockIdx.x * 256 + threadIdx.x; idx < total;
         idx += (size_t)gridDim.x * 256) {
        int pd = (int)(idx % PDIM);
        int bn = (int)(idx / PDIM);
        int n = bn % NPATCH, b = bn / NPATCH;
        int c = pd % 3, pix = pd / 3;
        int px = pix % 16, py = pix / 16;
        int hx = n % 14, hy = n / 14;
        int row = hy * 16 + py, col = hx * 16 + px;
        xp[idx] = f2bf(x[((size_t)(b * 3 + c) * 224 + row) * 224 + col]);
    }
}

__global__ __launch_bounds__(256)
void assemble_kernel(const float* __restrict__ e, const float* __restrict__ clstok,
                     const float* __restrict__ pos, float* __restrict__ U)
{
    const size_t total = (size_t)MTOK * DDIM;
    for (size_t idx = (size_t)blockIdx.x * 256 + threadIdx.x; idx < total;
         idx += (size_t)gridDim.x * 256) {
        int d = (int)(idx % DDIM);
        int bt = (int)(idx / DDIM);
        int t = bt % NTOK, b = bt / NTOK;
        float v = (t == 0) ? clstok[d] : e[((size_t)b * NPATCH + (t - 1)) * DDIM + d];
        U[idx] = v + pos[t * DDIM + d];
    }
}

__global__ __launch_bounds__(256)
void convert7_kernel(const float* s0, const float* s1, const float* s2,
                     const float* s3, const float* s4, const float* s5,
                     const float* s6, u16* __restrict__ dst)
{
    const int total4 = 1409024;  // 5636096/4
    for (int i4 = blockIdx.x * 256 + threadIdx.x; i4 < total4; i4 += gridDim.x * 256) {
        size_t e = (size_t)i4 * 4;
        const float* s; size_t off;
        if      (e < 393216)  { s = s0; off = 0; }
        else if (e < 1179648) { s = s1; off = 393216; }
        else if (e < 1441792) { s = s2; off = 1179648; }
        else if (e < 2490368) { s = s3; off = 1441792; }
        else if (e < 3538944) { s = s4; off = 2490368; }
        else if (e < 4587520) { s = s5; off = 3538944; }
        else                  { s = s6; off = 4587520; }
        float4 v = ((const float4*)s)[(e - off) >> 2];
        dst[e + 0] = f2bf(v.x); dst[e + 1] = f2bf(v.y);
        dst[e + 2] = f2bf(v.z); dst[e + 3] = f2bf(v.w);
    }
}

// ---------------------------------------------------------------------------
// MFMA attention (blocks 0..511) with optional fused halt-mean (blocks 512+).
// ---------------------------------------------------------------------------
template<int HM>
__global__ __launch_bounds__(256)
void attn_hm_kernel(const u16* __restrict__ qkv, u16* __restrict__ O,
                    const float* __restrict__ hsc, const float* __restrict__ bh2,
                    const float* __restrict__ U, float* __restrict__ halts,
                    float* __restrict__ cls, int lidx)
{
    __shared__ u16 Ks[208 * 64];
    __shared__ u16 Vt[64 * 208];
    __shared__ u16 Pl[4 * 16 * 208];

    if (HM && blockIdx.x >= 512) {
        int b = blockIdx.x - 512;
        int ln = threadIdx.x;
        if (ln >= 64) return;
        float bb = bh2[0];
        float s = 0.0f;
        for (int t = ln; t < NTOK; t += 64)
            s += 1.0f / (1.0f + expf(-(hsc[b * NTOK + t] + bb)));
        #pragma unroll
        for (int off = 32; off; off >>= 1) s += __shfl_xor(s, off, 64);
        if (ln == 0) halts[b * NLAYER + lidx] = s * (1.0f / (float)NTOK);
        for (int d = ln; d < DDIM; d += 64)
            cls[((size_t)b * NLAYER + lidx) * DDIM + d] = U[(size_t)b * NTOK * DDIM + d];
        return;
    }

    const int bh = blockIdx.x >> 1;
    const int half = blockIdx.x & 1;
    const int b = bh >> 3, h = bh & 7;
    const int tid = threadIdx.x;
    const int lane = tid & 63, wid = tid >> 6;
    const size_t base = ((size_t)b * NTOK) * 1536 + (size_t)h * 64;

    {
        int j0 = tid >> 3;
        int d0 = (tid & 7) * 8;
        for (int p = 0; p < 7; ++p) {
            int j = p * 32 + j0;
            if (j < 208) {
                bf16x8 v = {};
                if (j < NTOK) v = *(const bf16x8*)&qkv[base + (size_t)j * 1536 + 512 + d0];
                int byt = (j * 128 + d0 * 2) ^ ((j & 7) << 4);
                *(bf16x8*)((char*)Ks + byt) = v;
            }
        }
    }
    {
        int d = tid & 63;
        int jg = tid >> 6;
        for (int j = jg * 52; j < jg * 52 + 52; ++j) {
            u16 v = (j < NTOK) ? qkv[base + (size_t)j * 1536 + 1024 + d] : (u16)0;
            int byt = (d * 416 + j * 2) ^ ((d & 7) << 4);
            *(u16*)((char*)Vt + byt) = v;
        }
    }
    __syncthreads();

    u16* Pw = Pl + wid * 16 * 208;
    const float scale = 0.04419417382415922f;
    const int t0   = half ? 7 : 0;
    const int tcnt = half ? 6 : 7;
    const int g = lane >> 4;
    const int mycol = lane & 15;

    for (int ti = wid; ti < tcnt; ti += 4) {
        const int r0 = (t0 + ti) * 16;
        bf16x8 qf[2];
        #pragma unroll
        for (int ks = 0; ks < 2; ++ks) {
            int row = r0 + mycol;
            int col = ks * 32 + (g << 3);
            qf[ks] = *(const bf16x8*)&qkv[base + (size_t)row * 1536 + col];
        }
        f32x4 s[13];
        #pragma unroll
        for (int ct = 0; ct < 13; ++ct) s[ct] = (f32x4){0.f, 0.f, 0.f, 0.f};
        #pragma unroll
        for (int ks = 0; ks < 2; ++ks) {
            int kbyte = (ks * 32 + (g << 3)) * 2;
            #pragma unroll
            for (int ct = 0; ct < 13; ++ct) {
                int n = ct * 16 + mycol;
                bf16x8 kf = *(const bf16x8*)((char*)Ks + ((n * 128 + kbyte) ^ ((n & 7) << 4)));
                s[ct] = __builtin_amdgcn_mfma_f32_16x16x32_bf16(qf[ks], kf, s[ct], 0, 0, 0);
            }
        }
        float m[4], sum[4];
        #pragma unroll
        for (int j = 0; j < 4; ++j) m[j] = -1e30f;
        #pragma unroll
        for (int ct = 0; ct < 13; ++ct) {
            bool valid = (ct * 16 + mycol) < NTOK;
            #pragma unroll
            for (int j = 0; j < 4; ++j) {
                float v = valid ? s[ct][j] * scale : -1e30f;
                s[ct][j] = v;
                m[j] = fmaxf(m[j], v);
            }
        }
        #pragma unroll
        for (int off = 1; off < 16; off <<= 1)
            #pragma unroll
            for (int j = 0; j < 4; ++j) m[j] = fmaxf(m[j], __shfl_xor(m[j], off, 64));
        #pragma unroll
        for (int j = 0; j < 4; ++j) sum[j] = 0.0f;
        #pragma unroll
        for (int ct = 0; ct < 13; ++ct)
            #pragma unroll
            for (int j = 0; j < 4; ++j) {
                float e = expf(s[ct][j] - m[j]);
                s[ct][j] = e;
                sum[j] += e;
            }
        #pragma unroll
        for (int off = 1; off < 16; off <<= 1)
            #pragma unroll
            for (int j = 0; j < 4; ++j) sum[j] += __shfl_xor(sum[j], off, 64);
        float inv[4];
        #pragma unroll
        for (int j = 0; j < 4; ++j) inv[j] = 1.0f / sum[j];
        #pragma unroll
        for (int ct = 0; ct < 13; ++ct) {
            int col = ct * 16 + mycol;
            #pragma unroll
            for (int j = 0; j < 4; ++j) {
                int row = (g << 2) + j;
                int byt = (row * 416 + col * 2) ^ ((row & 7) << 4);
                *(u16*)((char*)Pw + byt) = f2bf(s[ct][j] * inv[j]);
            }
        }
        #pragma unroll
        for (int nt = 0; nt < 4; ++nt) {
            f32x4 o = (f32x4){0.f, 0.f, 0.f, 0.f};
            #pragma unroll
            for (int ks = 0; ks < 7; ++ks) {
                bf16x8 pf = {}, vf = {};
                bool live = !(ks == 6 && g >= 2);
                if (live) {
                    int kbyte = (ks * 32 + (g << 3)) * 2;
                    pf = *(const bf16x8*)((char*)Pw + ((mycol * 416 + kbyte) ^ ((mycol & 7) << 4)));
                    int vrow = nt * 16 + mycol;
                    vf = *(const bf16x8*)((char*)Vt + ((vrow * 416 + kbyte) ^ ((vrow & 7) << 4)));
                }
                o = __builtin_amdgcn_mfma_f32_16x16x32_bf16(pf, vf, o, 0, 0, 0);
            }
            #pragma unroll
            for (int j = 0; j < 4; ++j) {
                int grow = r0 + (g << 2) + j;
                if (grow < NTOK)
                    O[((size_t)b * NTOK + grow) * DDIM + h * 64 + nt * 16 + mycol] = f2bf(o[j]);
            }
        }
    }
}

__global__ __launch_bounds__(64)
void haltmean_kernel(const float* __restrict__ hsc, const float* __restrict__ bh2,
                     const float* __restrict__ U, float* __restrict__ halts,
                     float* __restrict__ cls, int lidx)
{
    int b = blockIdx.x, lane = threadIdx.x;
    float bb = bh2[0];
    float s = 0.0f;
    for (int t = lane; t < NTOK; t += 64)
        s += 1.0f / (1.0f + expf(-(hsc[b * NTOK + t] + bb)));
    #pragma unroll
    for (int off = 32; off; off >>= 1) s += __shfl_xor(s, off, 64);
    if (lane == 0) halts[b * NLAYER + lidx] = s * (1.0f / (float)NTOK);
    for (int d = lane; d < DDIM; d += 64)
        cls[((size_t)b * NLAYER + lidx) * DDIM + d] = U[(size_t)b * NTOK * DDIM + d];
}

__global__ __launch_bounds__(256)
void head_logits_kernel(const u16* __restrict__ Hh, const float* __restrict__ Wc2,
                        const float* __restrict__ bc2, float* __restrict__ logits)
{
    int wave = (blockIdx.x * 4) + (threadIdx.x >> 6);
    int lane = threadIdx.x & 63;
    if (wave >= BBATCH * NLAYER) return;
    const u16* row = Hh + (size_t)wave * MLPDIM;
    float rv[32];
    #pragma unroll
    for (int i = 0; i < 32; i++) rv[i] = bf2f(row[lane + i * 64]);
    #pragma unroll
    for (int c = 0; c < NCLASS; c++) {
        float s = 0.0f;
        #pragma unroll
        for (int i = 0; i < 32; i++) s = fmaf(rv[i], Wc2[c * MLPDIM + lane + i * 64], s);
        #pragma unroll
        for (int off = 32; off; off >>= 1) s += __shfl_xor(s, off, 64);
        if (lane == 0) logits[wave * NCLASS + c] = s + bc2[c];
    }
}

__global__ __launch_bounds__(256)
void celoss_kernel(const float* __restrict__ logits, const int* __restrict__ y,
                   const float* __restrict__ halts, float* __restrict__ out)
{
    __shared__ float ceS[BBATCH * NLAYER];
    __shared__ float bl[BBATCH];
    int tid = threadIdx.x;
    for (int r = tid; r < BBATCH * NLAYER; r += 256) {
        const float* lg = logits + (size_t)r * NCLASS;
        float mx = lg[0];
        #pragma unroll
        for (int i = 1; i < NCLASS; i++) mx = fmaxf(mx, lg[i]);
        float s = 0.0f;
        #pragma unroll
        for (int i = 0; i < NCLASS; i++) s += expf(lg[i] - mx);
        int lab = y[r / NLAYER];
        ceS[r] = -(lg[lab] - mx - logf(s));
    }
    __syncthreads();
    if (tid < BBATCH) {
        const float* c = ceS + tid * NLAYER;
        int idx = 0; float mn = c[0];
        for (int l = 1; l < NLAYER; l++) if (c[l] < mn) { mn = c[l]; idx = l; }
        idx += 1;
        float acc = 0.0f;
        for (int l = 0; l < idx; l++) {
            acc += c[l];
            float p = halts[tid * NLAYER + l];
            p = fminf(fmaxf(p, 1e-7f), 1.0f - 1e-7f);
            float hl = (l == idx - 1) ? 0.0f : 1.0f;
            acc += -(hl * logf(p) + (1.0f - hl) * log1pf(-p));
        }
        bl[tid] = acc / (float)idx;
    }
    __syncthreads();
    if (tid == 0) {
        float t = 0.0f;
        for (int b = 0; b < BBATCH; b++) t += bl[b];
        out[0] = t * (1.0f / (float)BBATCH);
    }
}

extern "C" void kernel_launch(void* const* d_in, const int* in_sizes, int n_in,
                              void* d_out, int out_size, void* d_ws, size_t ws_size,
                              hipStream_t stream)
{
    const float* x      = (const float*)d_in[0];
    const int*   y      = (const int*)d_in[1];
    const float* pos    = (const float*)d_in[2];
    const float* clstok = (const float*)d_in[3];
    const float* Wp     = (const float*)d_in[4];
    const float* bp     = (const float*)d_in[5];
    const float* Wqkv   = (const float*)d_in[6];
    const float* Wo     = (const float*)d_in[7];
    const float* bo     = (const float*)d_in[8];
    const float* ln1g   = (const float*)d_in[9];
    const float* ln1b   = (const float*)d_in[10];
    const float* ln2g   = (const float*)d_in[11];
    const float* ln2b   = (const float*)d_in[12];
    const float* W1     = (const float*)d_in[13];
    const float* b1     = (const float*)d_in[14];
    const float* W2     = (const float*)d_in[15];
    const float* b2     = (const float*)d_in[16];
    const float* lnhg   = (const float*)d_in[17];
    const float* lnhb   = (const float*)d_in[18];
    const float* Wh1    = (const float*)d_in[19];
    const float* bh1    = (const float*)d_in[20];
    const float* Wh2    = (const float*)d_in[21];
    const float* bh2    = (const float*)d_in[22];
    const float* lncg   = (const float*)d_in[23];
    const float* lncb   = (const float*)d_in[24];
    const float* Wc1    = (const float*)d_in[25];
    const float* bc1    = (const float*)d_in[26];
    const float* Wc2    = (const float*)d_in[27];
    const float* bc2    = (const float*)d_in[28];

    // ---- workspace layout ----
    float* U      = (float*)d_ws;                         // MTOK*512 f32
    float* CLS    = U + (size_t)MTOK * DDIM;              // 320*512
    float* LOGITS = CLS + (size_t)BBATCH * NLAYER * DDIM; // 3200
    float* HSC    = LOGITS + BBATCH * NLAYER * NCLASS;    // 10*MTOK
    float* HALTS  = HSC + (size_t)NLAYER * MTOK;          // 320
    u16* QKVb = (u16*)(HALTS + BBATCH * NLAYER + 32);     // QKVROWS*1536 (aliases EMB)
    float* EMB = (float*)QKVb;                            // MPATCH*512 f32 (pre-loop only)
    u16* LNB1 = QKVb + (size_t)QKVROWS * 1536;            // MPAD*512
    u16* LNB2 = LNB1 + (size_t)MPAD * DDIM;               // MPAD*512
    u16* LNBh = LNB2 + (size_t)MPAD * DDIM;               // MPAD*512
    u16* HB   = LNBh + (size_t)MPAD * DDIM;               // MPAD*2048 (aliases XP)
    u16* XP   = HB;                                       // MPATCH*768 (pre-loop only)
    u16* CLNB = HB + (size_t)MPAD * MLPDIM;               // 384*512
    u16* wWp  = CLNB + 384 * DDIM;
    u16* wWqkv= wWp   + 512 * 768;
    u16* wWo  = wWqkv + 1536 * 512;
    u16* wW1  = wWo   + 512 * 512;
    u16* wW2  = wW1   + 2048 * 512;
    u16* wWh1 = wW2   + 512 * 2048;
    u16* wWc1 = wWh1  + 2048 * 512;

    dim3 blk(256);
    const float* dummyF = bh2;

    // ---- setup ----
    convert7_kernel<<<dim3(1024), blk, 0, stream>>>(Wp, Wqkv, Wo, W1, W2, Wh1, Wc1, wWp);
    hipMemsetAsync(HSC, 0, (size_t)NLAYER * MTOK * sizeof(float), stream);
    patch_kernel<<<dim3(2048), blk, 0, stream>>>(x, XP);
    mgemm_kernel<0,1,0,0,0><<<dim3(4, 49), blk, 0, stream>>>(
        XP, wWp, bp, nullptr, (void*)EMB, MPATCH, DDIM, PDIM, PDIM, 49);
    assemble_kernel<<<dim3(2048), blk, 0, stream>>>(EMB, clstok, pos, U);
    ln_dual_kernel<<<dim3(256), blk, 0, stream>>>(U, ln1g, ln1b, lnhg, lnhb, LNB1, LNBh, MTOK);

    for (int l = 0; l < NLAYER; l++) {
        // 1: QKV GEMM (+ halt GEMM of layer l-1)
        if (l == 0) {
            gemm256_kernel<0,0><<<dim3(300), dim3(512), 0, stream>>>(
                300, 12, 12, LNB1, wWqkv, nullptr, (void*)QKVb, 1536,
                LNB1, wWqkv, nullptr, nullptr, (void*)QKVb, 1536, MTOK);
        } else {
            gemm256_kernel<0,1><<<dim3(700), dim3(512), 0, stream>>>(
                300, 12, 16, LNB1, wWqkv, nullptr, (void*)QKVb, 1536,
                LNBh, wWh1, bh1, Wh2, (void*)(HSC + (size_t)(l - 1) * MTOK), 2048, MTOK);
        }
        // 2: attn (+ halt-mean of layer l-1)
        if (l == 0) {
            attn_hm_kernel<0><<<dim3(512), blk, 0, stream>>>(
                QKVb, LNB1, nullptr, dummyF, U, HALTS, CLS, 0);
        } else {
            attn_hm_kernel<1><<<dim3(544), blk, 0, stream>>>(
                QKVb, LNB1, HSC + (size_t)(l - 1) * MTOK, bh2, U, HALTS, CLS, l - 1);
        }
        // 3: Wo + bias + residual -> U (f32)
        mgemm_kernel<0,1,1,0,0><<<dim3(4, 50), blk, 0, stream>>>(
            LNB1, wWo, bo, U, (void*)U, MTOK, DDIM, DDIM, DDIM, 50);
        // 4: ln2
        ln_one_kernel<<<dim3(256), blk, 0, stream>>>(U, ln2g, ln2b, LNB2, MTOK);
        // 5: W1 + bias + gelu -> HB (bf16)
        gemm256_kernel<2,2><<<dim3(400), dim3(512), 0, stream>>>(
            400, 16, 16, LNB2, wW1, b1, (void*)HB, 2048,
            LNB2, wW1, b1, nullptr, (void*)HB, 2048, MTOK);
        // 6: W2 split-K2, atomic += into U (bias on ks==0)
        mgemm_kernel<0,1,0,0,1><<<dim3(4, 100), blk, 0, stream>>>(
            HB, wW2, b2, nullptr, (void*)U, MTOK, DDIM, MLPDIM, 1024, 50);
        // 7: fused ln1 + lnh of new U
        ln_dual_kernel<<<dim3(256), blk, 0, stream>>>(
            U, ln1g, ln1b, lnhg, lnhb, LNB1, LNBh, MTOK);
    }

    // final halt GEMM (layer 9) + halt-mean
    gemm256_kernel<1,1><<<dim3(400), dim3(512), 0, stream>>>(
        400, 16, 16, LNBh, wWh1, bh1, (void*)(HSC + (size_t)9 * MTOK), 2048,
        LNBh, wWh1, bh1, Wh2, (void*)(HSC + (size_t)9 * MTOK), 2048, MTOK);
    haltmean_kernel<<<dim3(BBATCH), dim3(64), 0, stream>>>(
        HSC + (size_t)9 * MTOK, bh2, U, HALTS, CLS, 9);

    // head
    ln_one_kernel<<<dim3(80), blk, 0, stream>>>(CLS, lncg, lncb, CLNB, BBATCH * NLAYER);
    mgemm_kernel<1,1,0,1,0><<<dim3(16, 3), blk, 0, stream>>>(
        CLNB, wWc1, bc1, nullptr, (void*)HB, BBATCH * NLAYER, MLPDIM, DDIM, DDIM, 3);
    head_logits_kernel<<<dim3(80), blk, 0, stream>>>(HB, Wc2, bc2, LOGITS);
    celoss_kernel<<<dim3(1), blk, 0, stream>>>(LOGITS, y, HALTS, (float*)d_out);
}